// Round 13
// baseline (199.953 us; speedup 1.0000x reference)
//
#include <hip/hip_runtime.h>

#define B_ 1024
#define S_ 100
#define E_ 128
#define A_ 256
#define H_ 4

typedef __attribute__((ext_vector_type(4))) float f32x4;
typedef _Float16 f16;
typedef __attribute__((ext_vector_type(8))) _Float16 f16x8;
typedef unsigned short u16;
typedef unsigned int u32;

__device__ __forceinline__ u16 f2h(float x) {        // fp16 RNE, as bits
    return __builtin_bit_cast(u16, (f16)x);
}
__device__ __forceinline__ f32x4 mfma16h(f16x8 a, f16x8 b, f32x4 c) {
    return __builtin_amdgcn_mfma_f32_16x16x32_f16(a, b, c, 0, 0, 0);
}
// fp16 split of 8 floats (masked) — fallback kernel only
__device__ __forceinline__ void split8h(float4 a, float4 b, float msk, f16x8& hi, f16x8& lo) {
    float v[8] = { a.x, a.y, a.z, a.w, b.x, b.y, b.z, b.w };
    f16x8 H, L;
    #pragma unroll
    for (int j = 0; j < 8; ++j) {
        float x = v[j] * msk;
        f16 h = (f16)x;
        L[j] = (f16)(x - (float)h);
        H[j] = h;
    }
    hi = H; lo = L;
}
__device__ __forceinline__ void pack8h(float4 a, float4 b, float msk, f16x8& hi) {
    float v[8] = { a.x, a.y, a.z, a.w, b.x, b.y, b.z, b.w };
    f16x8 H;
    #pragma unroll
    for (int j = 0; j < 8; ++j) H[j] = (f16)(v[j] * msk);
    hi = H;
}
__device__ __forceinline__ f16x8 load_wfrag(const u16* wb, int t, int colbase, int lg, int lr) {
    return *reinterpret_cast<const f16x8*>(wb + ((((t * 4 + lg) * 256) + colbase + lr) << 3));
}

// ---------------- merged prep: blocks 0..1023 = unary softmax + q/k/v fp16 convert;
//                  blocks 1024..1027 = fp16 weight prep ----------------
__global__ __launch_bounds__(256) void prep2_kernel(
    const float* __restrict__ query, const float* __restrict__ key, const float* __restrict__ value,
    const float* __restrict__ Wu,
    const float* __restrict__ Wq, const float* __restrict__ Wk,
    const float* __restrict__ Wv, const float* __restrict__ Wres,
    float* __restrict__ su, u16* __restrict__ wbuf, u16* __restrict__ x16)
{
    const int t = threadIdx.x;
    if (blockIdx.x >= 1024) {
        const int z = blockIdx.x - 1024;   // 0:Wq 1:Wk 2:Wv 3:Wres (fp16 hi)
        const float* src = (z == 0) ? Wq : (z == 1) ? Wk : (z == 2) ? Wv : Wres;
        u16* dst = wbuf + (size_t)z * 32768;
        for (int i = t; i < E_ * A_; i += 256) {
            int e = i >> 8, col = i & 255;
            int ts = e >> 5, c = (e >> 3) & 3, j = e & 7;
            dst[(((ts * 4 + c) * 256 + col) << 3) + j] = f2h(src[i]);
        }
        return;
    }
    __shared__ float sm[S_ * H_];
    const int b = blockIdx.x;

    if (t < S_) {
        const float4* row = reinterpret_cast<const float4*>(key + ((size_t)b * S_ + t) * E_);
        const float4* wu4 = reinterpret_cast<const float4*>(Wu);
        float a0 = 0.f, a1 = 0.f, a2 = 0.f, a3 = 0.f;
        #pragma unroll 4
        for (int e4 = 0; e4 < E_ / 4; ++e4) {
            float4 kv = row[e4];
            float4 w0 = wu4[e4 * 4 + 0];
            float4 w1 = wu4[e4 * 4 + 1];
            float4 w2 = wu4[e4 * 4 + 2];
            float4 w3 = wu4[e4 * 4 + 3];
            a0 += kv.x * w0.x + kv.y * w1.x + kv.z * w2.x + kv.w * w3.x;
            a1 += kv.x * w0.y + kv.y * w1.y + kv.z * w2.y + kv.w * w3.y;
            a2 += kv.x * w0.z + kv.y * w1.z + kv.z * w2.z + kv.w * w3.z;
            a3 += kv.x * w0.w + kv.y * w1.w + kv.z * w2.w + kv.w * w3.w;
        }
        sm[t * 4 + 0] = a0; sm[t * 4 + 1] = a1;
        sm[t * 4 + 2] = a2; sm[t * 4 + 3] = a3;
    }
    __syncthreads();
    if (t < 128) {
        const int hh = t >> 5, i = t & 31;
        float m = -1e30f;
        for (int s = i; s < S_; s += 32) m = fmaxf(m, sm[s * 4 + hh]);
        #pragma unroll
        for (int o = 1; o < 32; o <<= 1) m = fmaxf(m, __shfl_xor(m, o, 32));
        float sum = 0.f;
        for (int s = i; s < S_; s += 32) sum += __expf(sm[s * 4 + hh] - m);
        #pragma unroll
        for (int o = 1; o < 32; o <<= 1) sum += __shfl_xor(sum, o, 32);
        float inv = 1.f / sum;
        for (int s = i; s < S_; s += 32) sm[s * 4 + hh] = __expf(sm[s * 4 + hh] - m) * inv;
    }
    __syncthreads();
    for (int i2 = t; i2 < S_ * H_; i2 += 256)
        su[(size_t)b * (S_ * H_) + i2] = sm[i2];

    const size_t per = (size_t)B_ * S_ * E_;
    const float* srcs[3] = { query, key, value };
    #pragma unroll
    for (int z = 0; z < 3; ++z) {
        const float4* s4 = reinterpret_cast<const float4*>(srcs[z] + (size_t)b * (S_ * E_));
        u16* dst = x16 + (size_t)z * per + (size_t)b * (S_ * E_);
        for (int i = t; i < (S_ * E_) / 4; i += 256) {
            float4 x = s4[i];
            ushort4 o = { f2h(x.x), f2h(x.y), f2h(x.z), f2h(x.w) };
            *reinterpret_cast<ushort4*>(dst + i * 4) = o;
        }
    }
}

// ---------------- 8-wave fused kernel: merged QKR cluster, v pre-B1, short post-B1 chain ----------------
__global__ __launch_bounds__(512, 4) void fusedC_kernel(
    const u16* __restrict__ xq16, const u16* __restrict__ xk16, const u16* __restrict__ xv16,
    const float* __restrict__ bres, const float* __restrict__ su,
    const u16* __restrict__ wbuf, float* __restrict__ out)
{
    __shared__ u32 smem[12896];               // 51584 B
    u16* qc   = (u16*)smem;                    // [112][72] fp16
    u16* kc   = (u16*)(smem + 4032);           // [112][72] fp16
    u16* vT   = (u16*)(smem + 8064);           // [64][128] fp16, xor-swz
    float* qmp  = (float*)(smem + 12160);      // [7][4][16] q col-sum partials
    float* rbuf = qmp + 448;                   // [112] r_j = qbar . k_j
    float* uwvb = rbuf + 112;                  // [64]
    float* subuf= uwvb + 64;                   // [112] su slice (tail zeroed)
    u16* pl = (u16*)smem;                      // P fp16 [112][136], aliases qc+kc

    const int bid = blockIdx.x;
    const int b = ((bid >> 5) << 3) | (bid & 7);   // XCD-grouped swizzle
    const int h = (bid >> 3) & 3;
    const int g = h * B_ + b;
    const int tid = threadIdx.x;
    const int l = tid & 63, w = tid >> 6;          // 8 waves
    const int lr = l & 15, lg = l >> 4;
    const int colb = h * 64;

    const u16* Xq = xq16 + (size_t)b * (S_ * E_);
    const u16* Xk = xk16 + (size_t)b * (S_ * E_);
    const u16* Xv = xv16 + (size_t)b * (S_ * E_);

    const u16* wqh = wbuf;
    const u16* wkh = wbuf + 32768;
    const u16* wvh = wbuf + 65536;
    const u16* wrh = wbuf + 98304;

    const int mt = w;                          // waves 0..6 own tiles 0..6; wave 7 = aux
    const bool act = (w < 7);
    const f32x4 Z4 = { 0.f, 0.f, 0.f, 0.f };

    const int row = mt * 16 + lr;
    const int rowc = (row < S_) ? row : S_ - 1;
    const u16* qp = Xq + (size_t)rowc * E_;
    const u16* kp = Xk + (size_t)rowc * E_;
    const u16* vp = Xv + (size_t)rowc * E_;

    // ---- issue ALL input loads up front (q,k,v) — hidden under the QKR cluster
    f16x8 aq[4], ak[4], av[4];
    if (act) {
        #pragma unroll
        for (int t = 0; t < 4; ++t)
            aq[t] = *reinterpret_cast<const f16x8*>(qp + t * 32 + lg * 8);
        #pragma unroll
        for (int t = 0; t < 4; ++t)
            ak[t] = *reinterpret_cast<const f16x8*>(kp + t * 32 + lg * 8);
        #pragma unroll
        for (int t = 0; t < 4; ++t)
            av[t] = *reinterpret_cast<const f16x8*>(vp + t * 32 + lg * 8);
    }

    // ---- su slice -> LDS (tail zero); vT tail cols zero
    if (tid < S_) subuf[tid] = su[(size_t)g * S_ + tid];
    else if (tid < 112) subuf[tid] = 0.f;
    #pragma unroll
    for (int i = 0; i < 2; ++i) {
        int q = tid * 2 + i;                   // 0..1023
        int d = q & 63, k = 112 + (q >> 6);
        vT[d * 128 + (((k >> 3) ^ (d & 7)) << 3) + (k & 7)] = 0;
    }

    // ---- merged QKR cluster: 48 MFMA, 12 independent chains
    f32x4 qa[4], ra[4], ka[4];
    #pragma unroll
    for (int n = 0; n < 4; ++n) { qa[n] = Z4; ra[n] = Z4; ka[n] = Z4; }
    f16x8 qhf[2];
    if (act) {
        __builtin_amdgcn_s_setprio(1);
        #pragma unroll
        for (int n = 0; n < 4; ++n)
            #pragma unroll
            for (int t = 0; t < 4; ++t) {
                f16x8 bq = load_wfrag(wqh, t, colb + n * 16, lg, lr);
                f16x8 br = load_wfrag(wrh, t, colb + n * 16, lg, lr);
                f16x8 bk = load_wfrag(wkh, t, colb + n * 16, lg, lr);
                qa[n] = mfma16h(aq[t], bq, qa[n]);
                ra[n] = mfma16h(aq[t], br, ra[n]);
                ka[n] = mfma16h(ak[t], bk, ka[n]);
            }
        __builtin_amdgcn_s_setprio(0);

        // qc/kc writes (uncentered fp16) + q column-sum partials (pad rows excluded)
        #pragma unroll
        for (int n = 0; n < 4; ++n)
            #pragma unroll
            for (int j = 0; j < 4; ++j) {
                qc[(mt * 16 + lg * 4 + j) * 72 + n * 16 + lr] = f2h(qa[n][j]);
                kc[(mt * 16 + lg * 4 + j) * 72 + n * 16 + lr] = f2h(ka[n][j]);
            }
        #pragma unroll
        for (int n = 0; n < 4; ++n) {
            float p = 0.f;
            #pragma unroll
            for (int j = 0; j < 4; ++j) {
                int rowj = mt * 16 + lg * 4 + j;
                p += (rowj < S_) ? qa[n][j] : 0.f;
            }
            p += __shfl_xor(p, 16, 64);
            p += __shfl_xor(p, 32, 64);
            if (lg == 0) qmp[(w * 4 + n) * 16 + lr] = p;
        }

        // ---- v cluster (av long in flight) -> vT, packed b64 writes
        f32x4 va[4];
        #pragma unroll
        for (int n = 0; n < 4; ++n) va[n] = Z4;
        __builtin_amdgcn_s_setprio(1);
        #pragma unroll
        for (int n = 0; n < 4; ++n)
            #pragma unroll
            for (int t = 0; t < 4; ++t) {
                f16x8 bh = load_wfrag(wvh, t, colb + n * 16, lg, lr);
                va[n] = mfma16h(av[t], bh, va[n]);
            }
        __builtin_amdgcn_s_setprio(0);
        #pragma unroll
        for (int n = 0; n < 4; ++n) {
            int r0 = mt * 16 + lg * 4;
            int d = n * 16 + lr;
            ushort4 o = { f2h(va[n][0]), f2h(va[n][1]), f2h(va[n][2]), f2h(va[n][3]) };
            *reinterpret_cast<ushort4*>(vT + d * 128 + (((r0 >> 3) ^ (d & 7)) << 3) + (r0 & 7)) = o;
        }

        // ---- pair A-frag: own-wave rows, written by this wave -> safe pre-barrier read
        #pragma unroll
        for (int t = 0; t < 2; ++t)
            qhf[t] = *reinterpret_cast<const f16x8*>(qc + (mt * 16 + lr) * 72 + t * 32 + lg * 8);
    }

    __syncthreads();                           // B1: qmp/qc/kc/vT visible

    // ---- post-B1 window: rj (VALU) + pair (MFMA) on act waves; uwv on wave 7
    f32x4 z[7];
    #pragma unroll
    for (int n = 0; n < 7; ++n) z[n] = Z4;
    if (act) {
        float qbar[4];
        #pragma unroll
        for (int n = 0; n < 4; ++n) {
            float s = 0.f;
            #pragma unroll
            for (int wv = 0; wv < 7; ++wv) s += qmp[(wv * 4 + n) * 16 + lr];
            qbar[n] = s * (1.f / S_);
        }
        float pr[4];
        #pragma unroll
        for (int j = 0; j < 4; ++j) {
            float s = 0.f;
            #pragma unroll
            for (int n = 0; n < 4; ++n) s += qbar[n] * ka[n][j];
            pr[j] = s;
        }
        #pragma unroll
        for (int o = 1; o < 16; o <<= 1)
            #pragma unroll
            for (int j = 0; j < 4; ++j) pr[j] += __shfl_xor(pr[j], o, 16);
        if (lr == 0)
            #pragma unroll
            for (int j = 0; j < 4; ++j) rbuf[mt * 16 + lg * 4 + j] = pr[j];

        __builtin_amdgcn_s_setprio(1);
        #pragma unroll
        for (int n = 0; n < 7; ++n)
            #pragma unroll
            for (int t = 0; t < 2; ++t) {
                f16x8 bh = *reinterpret_cast<const f16x8*>(kc + (n * 16 + lr) * 72 + t * 32 + lg * 8);
                z[n] = mfma16h(qhf[t], bh, z[n]);
            }
        __builtin_amdgcn_s_setprio(0);
    } else {
        const int d = l;
        float acc = 0.f;
        #pragma unroll
        for (int c = 0; c < 13; ++c) {         // chunks 0..12; subuf[100..111] = 0
            f16x8 vv = *reinterpret_cast<const f16x8*>(vT + d * 128 + ((c ^ (d & 7)) << 3));
            #pragma unroll
            for (int j = 0; j < 8; ++j) acc += subuf[c * 8 + j] * (float)vv[j];
        }
        uwvb[d] = acc;
    }
    __syncthreads();                           // B2: rbuf (and uwvb) visible

    // ---- subtract r_j, mask invalid cols, softmax over k (in-register)
    if (act) {
        #pragma unroll
        for (int n = 0; n < 7; ++n) {
            float rr = rbuf[n * 16 + lr];
            #pragma unroll
            for (int j = 0; j < 4; ++j) z[n][j] -= rr;
        }
        if (lr >= 4) {                         // cols 100..111 invalid
            f32x4 NEG = { -1e30f, -1e30f, -1e30f, -1e30f };
            z[6] = NEG;
        }
        #pragma unroll
        for (int j = 0; j < 4; ++j) {
            float m = z[0][j];
            #pragma unroll
            for (int n = 1; n < 7; ++n) m = fmaxf(m, z[n][j]);
            #pragma unroll
            for (int o = 1; o < 16; o <<= 1) m = fmaxf(m, __shfl_xor(m, o, 16));
            float s = 0.f;
            #pragma unroll
            for (int n = 0; n < 7; ++n) { float p = __expf(z[n][j] - m); z[n][j] = p; s += p; }
            #pragma unroll
            for (int o = 1; o < 16; o <<= 1) s += __shfl_xor(s, o, 16);
            float inv = 1.f / s;
            #pragma unroll
            for (int n = 0; n < 7; ++n) z[n][j] *= inv;
        }
    }
    __syncthreads();                           // B3: all qc/kc reads done (pl aliases qc/kc)

    // ---- write P (fp16 RNE); cols 112..127 zeroed
    if (act) {
        #pragma unroll
        for (int n = 0; n < 7; ++n)
            #pragma unroll
            for (int j = 0; j < 4; ++j) {
                int r = mt * 16 + lg * 4 + j;
                pl[r * 136 + n * 16 + lr] = f2h(z[n][j]);
            }
        #pragma unroll
        for (int j = 0; j < 4; ++j) {
            int r = mt * 16 + lg * 4 + j;
            pl[r * 136 + 112 + lr] = 0;
        }
    }
    __syncthreads();                           // B4: P + vT + uwvb ready

    // ---- PV (fp16) + epilogue
    if (act) {
        f16x8 pa[4];
        #pragma unroll
        for (int t = 0; t < 4; ++t)
            pa[t] = *reinterpret_cast<const f16x8*>(pl + (mt * 16 + lr) * 136 + t * 32 + lg * 8);
        f32x4 pv[4];
        #pragma unroll
        for (int n = 0; n < 4; ++n) pv[n] = Z4;
        __builtin_amdgcn_s_setprio(1);
        #pragma unroll
        for (int n = 0; n < 4; ++n)
            #pragma unroll
            for (int t = 0; t < 4; ++t) {
                int d = n * 16 + lr;
                f16x8 bv = *reinterpret_cast<const f16x8*>(vT + d * 128 + ((((t * 4 + lg)) ^ (d & 7)) << 3));
                pv[n] = mfma16h(pa[t], bv, pv[n]);
            }
        __builtin_amdgcn_s_setprio(0);

        #pragma unroll
        for (int n = 0; n < 4; ++n) {
            int d = n * 16 + lr;
            float add = bres[colb + d] + uwvb[d];
            #pragma unroll
            for (int j = 0; j < 4; ++j) {
                int r = mt * 16 + lg * 4 + j;
                if (r < S_) {
                    float val = ra[n][j] + pv[n][j] + add;
                    __builtin_nontemporal_store(val, &out[((size_t)b * S_ + r) * A_ + colb + d]);
                }
            }
        }
    }
}

// ---------------- fallback fused kernel (fp32 inputs, 2-term q/k) — used only if ws too small ----------------
__global__ __launch_bounds__(256, 3) void fused8_kernel(
    const float* __restrict__ query, const float* __restrict__ key, const float* __restrict__ value,
    const float* __restrict__ bres, const float* __restrict__ su,
    const u16* __restrict__ wbuf, float* __restrict__ out)
{
    __shared__ u32 smem[12704];
    u16* qc   = (u16*)smem;
    u16* kc   = (u16*)(smem + 4032);
    u16* vT   = (u16*)(smem + 8064);
    float* qmp  = (float*)(smem + 12160);
    float* rbuf = qmp + 256;
    float* uwvb = rbuf + 112;
    float* subuf= uwvb + 64;
    u16* pl = (u16*)smem;

    const int bid = blockIdx.x;
    const int b = ((bid >> 5) << 3) | (bid & 7);
    const int h = (bid >> 3) & 3;
    const int g = h * B_ + b;
    const int tid = threadIdx.x;
    const int l = tid & 63, w = tid >> 6;
    const int lr = l & 15, lg = l >> 4;
    const int colb = h * 64;

    const float* Xq = query + (size_t)b * (S_ * E_);
    const float* Xk = key   + (size_t)b * (S_ * E_);
    const float* Xv = value + (size_t)b * (S_ * E_);

    const u16* wqh = wbuf;
    const u16* wkh = wbuf + 32768;
    const u16* wvh = wbuf + 65536;
    const u16* wrh = wbuf + 98304;

    const int mt0 = w;
    const int mt1 = (w < 3) ? (w + 4) : 3;
    const int mt[2] = { mt0, mt1 };
    const float dupg = (w == 3) ? 0.f : 1.f;
    const f32x4 Z4 = { 0.f, 0.f, 0.f, 0.f };

    const int row0 = mt0 * 16 + lr, row1 = mt1 * 16 + lr;
    const float msk[2] = { (row0 < S_) ? 1.f : 0.f, (row1 < S_) ? 1.f : 0.f };
    const float* qp[2] = { Xq + (size_t)((row0 < S_) ? row0 : S_ - 1) * E_,
                           Xq + (size_t)((row1 < S_) ? row1 : S_ - 1) * E_ };
    const float* kp[2] = { Xk + (size_t)((row0 < S_) ? row0 : S_ - 1) * E_,
                           Xk + (size_t)((row1 < S_) ? row1 : S_ - 1) * E_ };
    const float* vp[2] = { Xv + (size_t)((row0 < S_) ? row0 : S_ - 1) * E_,
                           Xv + (size_t)((row1 < S_) ? row1 : S_ - 1) * E_ };

    float4 qr[2][4][2], kr[2][4][2];
    #pragma unroll
    for (int im = 0; im < 2; ++im)
        #pragma unroll
        for (int t = 0; t < 4; ++t) {
            qr[im][t][0] = *reinterpret_cast<const float4*>(qp[im] + t * 32 + lg * 8);
            qr[im][t][1] = *reinterpret_cast<const float4*>(qp[im] + t * 32 + lg * 8 + 4);
        }
    #pragma unroll
    for (int im = 0; im < 2; ++im)
        #pragma unroll
        for (int t = 0; t < 4; ++t) {
            kr[im][t][0] = *reinterpret_cast<const float4*>(kp[im] + t * 32 + lg * 8);
            kr[im][t][1] = *reinterpret_cast<const float4*>(kp[im] + t * 32 + lg * 8 + 4);
        }

    if (tid < S_) subuf[tid] = su[(size_t)g * S_ + tid];
    else if (tid < 112) subuf[tid] = 0.f;
    #pragma unroll
    for (int i = 0; i < 4; ++i) {
        int q = tid * 4 + i;
        int d = q & 63, k = 112 + (q >> 6);
        vT[d * 128 + (((k >> 3) ^ (d & 7)) << 3) + (k & 7)] = 0;
    }

    f16x8 ah[2][4], al[2][4];
    #pragma unroll
    for (int im = 0; im < 2; ++im)
        #pragma unroll
        for (int t = 0; t < 4; ++t)
            split8h(qr[im][t][0], qr[im][t][1], msk[im], ah[im][t], al[im][t]);

    f32x4 qa[2][4], ra[2][4];
    #pragma unroll
    for (int im = 0; im < 2; ++im)
        #pragma unroll
        for (int n = 0; n < 4; ++n) { qa[im][n] = Z4; ra[im][n] = Z4; }
    #pragma unroll
    for (int n = 0; n < 4; ++n)
        #pragma unroll
        for (int t = 0; t < 4; ++t) {
            f16x8 bh = load_wfrag(wqh, t, colb + n * 16, lg, lr);
            f16x8 br = load_wfrag(wrh, t, colb + n * 16, lg, lr);
            #pragma unroll
            for (int im = 0; im < 2; ++im) {
                qa[im][n] = mfma16h(ah[im][t], bh, qa[im][n]);
                qa[im][n] = mfma16h(al[im][t], bh, qa[im][n]);
                ra[im][n] = mfma16h(ah[im][t], br, ra[im][n]);
            }
        }
    #pragma unroll
    for (int im = 0; im < 2; ++im)
        #pragma unroll
        for (int n = 0; n < 4; ++n)
            #pragma unroll
            for (int j = 0; j < 4; ++j)
                qc[(mt[im] * 16 + lg * 4 + j) * 72 + n * 16 + lr] = f2h(qa[im][n][j]);
    #pragma unroll
    for (int n = 0; n < 4; ++n) {
        float p = 0.f;
        #pragma unroll
        for (int j = 0; j < 4; ++j) p += qa[0][n][j];
        float p1 = 0.f;
        #pragma unroll
        for (int j = 0; j < 4; ++j) p1 += qa[1][n][j];
        p += dupg * p1;
        p += __shfl_xor(p, 16, 64);
        p += __shfl_xor(p, 32, 64);
        if (lg == 0) qmp[(w * 4 + n) * 16 + lr] = p;
    }

    float4 vr[2][4][2];
    #pragma unroll
    for (int im = 0; im < 2; ++im)
        #pragma unroll
        for (int t = 0; t < 4; ++t) {
            vr[im][t][0] = *reinterpret_cast<const float4*>(vp[im] + t * 32 + lg * 8);
            vr[im][t][1] = *reinterpret_cast<const float4*>(vp[im] + t * 32 + lg * 8 + 4);
        }
    #pragma unroll
    for (int im = 0; im < 2; ++im)
        #pragma unroll
        for (int t = 0; t < 4; ++t)
            split8h(kr[im][t][0], kr[im][t][1], msk[im], ah[im][t], al[im][t]);

    f32x4 ka[2][4];
    #pragma unroll
    for (int im = 0; im < 2; ++im)
        #pragma unroll
        for (int n = 0; n < 4; ++n) ka[im][n] = Z4;
    #pragma unroll
    for (int n = 0; n < 4; ++n)
        #pragma unroll
        for (int t = 0; t < 4; ++t) {
            f16x8 bh = load_wfrag(wkh, t, colb + n * 16, lg, lr);
            #pragma unroll
            for (int im = 0; im < 2; ++im) {
                ka[im][n] = mfma16h(ah[im][t], bh, ka[im][n]);
                ka[im][n] = mfma16h(al[im][t], bh, ka[im][n]);
            }
        }
    #pragma unroll
    for (int im = 0; im < 2; ++im)
        #pragma unroll
        for (int n = 0; n < 4; ++n)
            #pragma unroll
            for (int j = 0; j < 4; ++j)
                kc[(mt[im] * 16 + lg * 4 + j) * 72 + n * 16 + lr] = f2h(ka[im][n][j]);

    __syncthreads();

    {
        float qbar[4];
        #pragma unroll
        for (int n = 0; n < 4; ++n) {
            float s = 0.f;
            #pragma unroll
            for (int wv = 0; wv < 4; ++wv) s += qmp[(wv * 4 + n) * 16 + lr];
            qbar[n] = s * (1.f / S_);
        }
        #pragma unroll
        for (int im = 0; im < 2; ++im) {
            float pr[4];
            #pragma unroll
            for (int j = 0; j < 4; ++j) {
                float s = 0.f;
                #pragma unroll
                for (int n = 0; n < 4; ++n) s += qbar[n] * ka[im][n][j];
                pr[j] = s;
            }
            #pragma unroll
            for (int o = 1; o < 16; o <<= 1)
                #pragma unroll
                for (int j = 0; j < 4; ++j) pr[j] += __shfl_xor(pr[j], o, 16);
            if (lr == 0)
                #pragma unroll
                for (int j = 0; j < 4; ++j) rbuf[mt[im] * 16 + lg * 4 + j] = pr[j];
        }
    }

    #pragma unroll
    for (int im = 0; im < 2; ++im)
        #pragma unroll
        for (int t = 0; t < 4; ++t)
            pack8h(vr[im][t][0], vr[im][t][1], msk[im], ah[im][t]);
    {
        f32x4 va[2][4];
        #pragma unroll
        for (int im = 0; im < 2; ++im)
            #pragma unroll
            for (int n = 0; n < 4; ++n) va[im][n] = Z4;
        #pragma unroll
        for (int n = 0; n < 4; ++n)
            #pragma unroll
            for (int t = 0; t < 4; ++t) {
                f16x8 bh = load_wfrag(wvh, t, colb + n * 16, lg, lr);
                #pragma unroll
                for (int im = 0; im < 2; ++im)
                    va[im][n] = mfma16h(ah[im][t], bh, va[im][n]);
            }
        #pragma unroll
        for (int im = 0; im < 2; ++im)
            #pragma unroll
            for (int n = 0; n < 4; ++n)
                #pragma unroll
                for (int j = 0; j < 4; ++j) {
                    int r = mt[im] * 16 + lg * 4 + j;
                    int d = n * 16 + lr;
                    vT[d * 128 + (((r >> 3) ^ (d & 7)) << 3) + (r & 7)] = f2h(va[im][n][j]);
                }
    }
    __syncthreads();

    f16x8 qhf[2][2];
    #pragma unroll
    for (int im = 0; im < 2; ++im)
        #pragma unroll
        for (int t = 0; t < 2; ++t)
            qhf[im][t] = *reinterpret_cast<const f16x8*>(qc + (mt[im] * 16 + lr) * 72 + t * 32 + lg * 8);
    f32x4 z[2][7];
    #pragma unroll
    for (int im = 0; im < 2; ++im)
        #pragma unroll
        for (int n = 0; n < 7; ++n) z[im][n] = Z4;
    #pragma unroll
    for (int n = 0; n < 7; ++n)
        #pragma unroll
        for (int t = 0; t < 2; ++t) {
            f16x8 bh = *reinterpret_cast<const f16x8*>(kc + (n * 16 + lr) * 72 + t * 32 + lg * 8);
            #pragma unroll
            for (int im = 0; im < 2; ++im)
                z[im][n] = mfma16h(qhf[im][t], bh, z[im][n]);
        }

    {
        const int d = w * 16 + lr;
        float acc = 0.f;
        #pragma unroll
        for (int c = 0; c < 3; ++c) {
            int k8 = lg + c * 4;
            f16x8 vv = *reinterpret_cast<const f16x8*>(vT + d * 128 + ((k8 ^ (d & 7)) << 3));
            #pragma unroll
            for (int j = 0; j < 8; ++j) acc += subuf[k8 * 8 + j] * (float)vv[j];
        }
        if (lg == 0) {
            f16x8 vv = *reinterpret_cast<const f16x8*>(vT + d * 128 + ((12 ^ (d & 7)) << 3));
            #pragma unroll
            for (int j = 0; j < 8; ++j) acc += subuf[96 + j] * (float)vv[j];
        }
        acc += __shfl_xor(acc, 16, 64);
        acc += __shfl_xor(acc, 32, 64);
        if (lg == 0) uwvb[d] = acc;
    }

    #pragma unroll
    for (int im = 0; im < 2; ++im) {
        #pragma unroll
        for (int n = 0; n < 7; ++n) {
            float rr = rbuf[n * 16 + lr];
            #pragma unroll
            for (int j = 0; j < 4; ++j) z[im][n][j] -= rr;
        }
        if (lr >= 4) {
            f32x4 NEG = { -1e30f, -1e30f, -1e30f, -1e30f };
            z[im][6] = NEG;
        }
        #pragma unroll
        for (int j = 0; j < 4; ++j) {
            float m = z[im][0][j];
            #pragma unroll
            for (int n = 1; n < 7; ++n) m = fmaxf(m, z[im][n][j]);
            #pragma unroll
            for (int o = 1; o < 16; o <<= 1) m = fmaxf(m, __shfl_xor(m, o, 16));
            float s = 0.f;
            #pragma unroll
            for (int n = 0; n < 7; ++n) { float p = __expf(z[im][n][j] - m); z[im][n][j] = p; s += p; }
            #pragma unroll
            for (int o = 1; o < 16; o <<= 1) s += __shfl_xor(s, o, 16);
            float inv = 1.f / s;
            #pragma unroll
            for (int n = 0; n < 7; ++n) z[im][n][j] *= inv;
        }
    }
    __syncthreads();

    #pragma unroll
    for (int im = 0; im < 2; ++im) {
        #pragma unroll
        for (int n = 0; n < 7; ++n)
            #pragma unroll
            for (int j = 0; j < 4; ++j) {
                int row = mt[im] * 16 + lg * 4 + j;
                pl[row * 136 + n * 16 + lr] = f2h(z[im][n][j]);
            }
        #pragma unroll
        for (int j = 0; j < 4; ++j) {
            int row = mt[im] * 16 + lg * 4 + j;
            pl[row * 136 + 112 + lr] = 0;
        }
    }
    __syncthreads();

    f16x8 pa[2][4];
    #pragma unroll
    for (int im = 0; im < 2; ++im)
        #pragma unroll
        for (int t = 0; t < 4; ++t)
            pa[im][t] = *reinterpret_cast<const f16x8*>(pl + (mt[im] * 16 + lr) * 136 + t * 32 + lg * 8);
    f32x4 pv[2][4];
    #pragma unroll
    for (int im = 0; im < 2; ++im)
        #pragma unroll
        for (int n = 0; n < 4; ++n) pv[im][n] = Z4;
    #pragma unroll
    for (int n = 0; n < 4; ++n)
        #pragma unroll
        for (int t = 0; t < 4; ++t) {
            int d = n * 16 + lr;
            f16x8 bv = *reinterpret_cast<const f16x8*>(vT + d * 128 + ((((t * 4 + lg)) ^ (d & 7)) << 3));
            #pragma unroll
            for (int im = 0; im < 2; ++im)
                pv[im][n] = mfma16h(pa[im][t], bv, pv[im][n]);
        }

    float bv4[4];
    #pragma unroll
    for (int n = 0; n < 4; ++n) bv4[n] = bres[colb + n * 16 + lr];
    #pragma unroll
    for (int im = 0; im < 2; ++im)
        #pragma unroll
        for (int n = 0; n < 4; ++n) {
            int d = n * 16 + lr;
            float add = bv4[n] + uwvb[d];
            #pragma unroll
            for (int j = 0; j < 4; ++j) {
                int row = mt[im] * 16 + lg * 4 + j;
                if (row < S_) {
                    float val = ra[im][n][j] + pv[im][n][j] + add;
                    __builtin_nontemporal_store(val, &out[((size_t)b * S_ + row) * A_ + colb + d]);
                }
            }
        }
}

extern "C" void kernel_launch(void* const* d_in, const int* in_sizes, int n_in,
                              void* d_out, int out_size, void* d_ws, size_t ws_size,
                              hipStream_t stream) {
    const float* query = (const float*)d_in[0];
    const float* key   = (const float*)d_in[1];
    const float* value = (const float*)d_in[2];
    const float* Wq    = (const float*)d_in[3];
    const float* Wk    = (const float*)d_in[4];
    const float* Wv    = (const float*)d_in[5];
    const float* Wu    = (const float*)d_in[6];
    const float* Wres  = (const float*)d_in[7];
    const float* bres  = (const float*)d_in[8];
    float* out = (float*)d_out;

    float* su  = (float*)d_ws;                          // 1.6384 MB
    u16*  wbuf = (u16*)((char*)d_ws + 1638400);         // 4 * 64 KB fp16 weights
    u16*  x16  = (u16*)((char*)d_ws + 2162688);         // 3 * 25.6 MB fp16 q/k/v

    const size_t need = 2162688u + 3u * (size_t)B_ * S_ * E_ * 2u;   // ~80.8 MB

    prep2_kernel<<<1028, 256, 0, stream>>>(query, key, value, Wu, Wq, Wk, Wv, Wres, su, wbuf, x16);
    if (ws_size >= need) {
        fusedC_kernel<<<B_ * H_, 512, 0, stream>>>(
            x16, x16 + (size_t)B_ * S_ * E_, x16 + 2u * (size_t)B_ * S_ * E_,
            bres, su, wbuf, out);
    } else {
        fused8_kernel<<<B_ * H_, 256, 0, stream>>>(query, key, value, bres, su, wbuf, out);
    }
}

// Round 14
// 187.329 us; speedup vs baseline: 1.0674x; 1.0674x over previous
//
#include <hip/hip_runtime.h>

#define B_ 1024
#define S_ 100
#define E_ 128
#define A_ 256
#define H_ 4

typedef __attribute__((ext_vector_type(4))) float f32x4;
typedef _Float16 f16;
typedef __attribute__((ext_vector_type(8))) _Float16 f16x8;
typedef unsigned short u16;
typedef unsigned int u32;

__device__ __forceinline__ u16 f2h(float x) {        // fp16 RNE, as bits
    return __builtin_bit_cast(u16, (f16)x);
}
__device__ __forceinline__ f32x4 mfma16h(f16x8 a, f16x8 b, f32x4 c) {
    return __builtin_amdgcn_mfma_f32_16x16x32_f16(a, b, c, 0, 0, 0);
}
// fp16 split of 8 floats (masked) — fallback kernel only
__device__ __forceinline__ void split8h(float4 a, float4 b, float msk, f16x8& hi, f16x8& lo) {
    float v[8] = { a.x, a.y, a.z, a.w, b.x, b.y, b.z, b.w };
    f16x8 H, L;
    #pragma unroll
    for (int j = 0; j < 8; ++j) {
        float x = v[j] * msk;
        f16 h = (f16)x;
        L[j] = (f16)(x - (float)h);
        H[j] = h;
    }
    hi = H; lo = L;
}
__device__ __forceinline__ void pack8h(float4 a, float4 b, float msk, f16x8& hi) {
    float v[8] = { a.x, a.y, a.z, a.w, b.x, b.y, b.z, b.w };
    f16x8 H;
    #pragma unroll
    for (int j = 0; j < 8; ++j) H[j] = (f16)(v[j] * msk);
    hi = H;
}
__device__ __forceinline__ f16x8 load_wfrag(const u16* wb, int t, int colbase, int lg, int lr) {
    return *reinterpret_cast<const f16x8*>(wb + ((((t * 4 + lg) * 256) + colbase + lr) << 3));
}

// ---------------- merged prep: blocks 0..1023 = unary softmax + q/k/v fp16 convert;
//                  blocks 1024..1027 = fp16 weight prep ----------------
__global__ __launch_bounds__(256) void prep2_kernel(
    const float* __restrict__ query, const float* __restrict__ key, const float* __restrict__ value,
    const float* __restrict__ Wu,
    const float* __restrict__ Wq, const float* __restrict__ Wk,
    const float* __restrict__ Wv, const float* __restrict__ Wres,
    float* __restrict__ su, u16* __restrict__ wbuf, u16* __restrict__ x16)
{
    const int t = threadIdx.x;
    if (blockIdx.x >= 1024) {
        const int z = blockIdx.x - 1024;   // 0:Wq 1:Wk 2:Wv 3:Wres (fp16 hi)
        const float* src = (z == 0) ? Wq : (z == 1) ? Wk : (z == 2) ? Wv : Wres;
        u16* dst = wbuf + (size_t)z * 32768;
        for (int i = t; i < E_ * A_; i += 256) {
            int e = i >> 8, col = i & 255;
            int ts = e >> 5, c = (e >> 3) & 3, j = e & 7;
            dst[(((ts * 4 + c) * 256 + col) << 3) + j] = f2h(src[i]);
        }
        return;
    }
    __shared__ float sm[S_ * H_];
    const int b = blockIdx.x;

    if (t < S_) {
        const float4* row = reinterpret_cast<const float4*>(key + ((size_t)b * S_ + t) * E_);
        const float4* wu4 = reinterpret_cast<const float4*>(Wu);
        float a0 = 0.f, a1 = 0.f, a2 = 0.f, a3 = 0.f;
        #pragma unroll 4
        for (int e4 = 0; e4 < E_ / 4; ++e4) {
            float4 kv = row[e4];
            float4 w0 = wu4[e4 * 4 + 0];
            float4 w1 = wu4[e4 * 4 + 1];
            float4 w2 = wu4[e4 * 4 + 2];
            float4 w3 = wu4[e4 * 4 + 3];
            a0 += kv.x * w0.x + kv.y * w1.x + kv.z * w2.x + kv.w * w3.x;
            a1 += kv.x * w0.y + kv.y * w1.y + kv.z * w2.y + kv.w * w3.y;
            a2 += kv.x * w0.z + kv.y * w1.z + kv.z * w2.z + kv.w * w3.z;
            a3 += kv.x * w0.w + kv.y * w1.w + kv.z * w2.w + kv.w * w3.w;
        }
        sm[t * 4 + 0] = a0; sm[t * 4 + 1] = a1;
        sm[t * 4 + 2] = a2; sm[t * 4 + 3] = a3;
    }
    __syncthreads();
    if (t < 128) {
        const int hh = t >> 5, i = t & 31;
        float m = -1e30f;
        for (int s = i; s < S_; s += 32) m = fmaxf(m, sm[s * 4 + hh]);
        #pragma unroll
        for (int o = 1; o < 32; o <<= 1) m = fmaxf(m, __shfl_xor(m, o, 32));
        float sum = 0.f;
        for (int s = i; s < S_; s += 32) sum += __expf(sm[s * 4 + hh] - m);
        #pragma unroll
        for (int o = 1; o < 32; o <<= 1) sum += __shfl_xor(sum, o, 32);
        float inv = 1.f / sum;
        for (int s = i; s < S_; s += 32) sm[s * 4 + hh] = __expf(sm[s * 4 + hh] - m) * inv;
    }
    __syncthreads();
    for (int i2 = t; i2 < S_ * H_; i2 += 256)
        su[(size_t)b * (S_ * H_) + i2] = sm[i2];

    const size_t per = (size_t)B_ * S_ * E_;
    const float* srcs[3] = { query, key, value };
    #pragma unroll
    for (int z = 0; z < 3; ++z) {
        const float4* s4 = reinterpret_cast<const float4*>(srcs[z] + (size_t)b * (S_ * E_));
        u16* dst = x16 + (size_t)z * per + (size_t)b * (S_ * E_);
        for (int i = t; i < (S_ * E_) / 4; i += 256) {
            float4 x = s4[i];
            ushort4 o = { f2h(x.x), f2h(x.y), f2h(x.z), f2h(x.w) };
            *reinterpret_cast<ushort4*>(dst + i * 4) = o;
        }
    }
}

// ---------------- 8-wave fused kernel: 128-VGPR cap, batched weight-frag loads ----------------
__global__ __launch_bounds__(512, 2) void fusedD_kernel(
    const u16* __restrict__ xq16, const u16* __restrict__ xk16, const u16* __restrict__ xv16,
    const float* __restrict__ bres, const float* __restrict__ su,
    const u16* __restrict__ wbuf, float* __restrict__ out)
{
    __shared__ u32 smem[12896];               // 51584 B
    u16* qc   = (u16*)smem;                    // [112][72] fp16
    u16* kc   = (u16*)(smem + 4032);           // [112][72] fp16
    u16* vT   = (u16*)(smem + 8064);           // [64][128] fp16, xor-swz
    float* qmp  = (float*)(smem + 12160);      // [7][4][16] q col-sum partials
    float* rbuf = qmp + 448;                   // [112] r_j = qbar . k_j
    float* uwvb = rbuf + 112;                  // [64]
    float* subuf= uwvb + 64;                   // [112] su slice (tail zeroed)
    u16* pl = (u16*)smem;                      // P fp16 [112][136], aliases qc+kc

    const int bid = blockIdx.x;
    const int b = ((bid >> 5) << 3) | (bid & 7);   // XCD-grouped swizzle
    const int h = (bid >> 3) & 3;
    const int g = h * B_ + b;
    const int tid = threadIdx.x;
    const int l = tid & 63, w = tid >> 6;          // 8 waves
    const int lr = l & 15, lg = l >> 4;
    const int colb = h * 64;

    const u16* Xq = xq16 + (size_t)b * (S_ * E_);
    const u16* Xk = xk16 + (size_t)b * (S_ * E_);
    const u16* Xv = xv16 + (size_t)b * (S_ * E_);

    const u16* wqh = wbuf;
    const u16* wkh = wbuf + 32768;
    const u16* wvh = wbuf + 65536;
    const u16* wrh = wbuf + 98304;

    const int mt = w;                          // waves 0..6 own tiles 0..6; wave 7 = aux
    const bool act = (w < 7);
    const f32x4 Z4 = { 0.f, 0.f, 0.f, 0.f };

    const int row = mt * 16 + lr;
    const int rowc = (row < S_) ? row : S_ - 1;
    const u16* qp = Xq + (size_t)rowc * E_;
    const u16* kp = Xk + (size_t)rowc * E_;
    const u16* vp = Xv + (size_t)rowc * E_;

    // ---- issue q,k input loads up front
    f16x8 aq[4], ak[4], av[4];
    if (act) {
        #pragma unroll
        for (int t = 0; t < 4; ++t)
            aq[t] = *reinterpret_cast<const f16x8*>(qp + t * 32 + lg * 8);
        #pragma unroll
        for (int t = 0; t < 4; ++t)
            ak[t] = *reinterpret_cast<const f16x8*>(kp + t * 32 + lg * 8);
    }

    // ---- su slice -> LDS (tail zero); vT tail cols zero
    if (tid < S_) subuf[tid] = su[(size_t)g * S_ + tid];
    else if (tid < 112) subuf[tid] = 0.f;
    #pragma unroll
    for (int i = 0; i < 2; ++i) {
        int q = tid * 2 + i;                   // 0..1023
        int d = q & 63, k = 112 + (q >> 6);
        vT[d * 128 + (((k >> 3) ^ (d & 7)) << 3) + (k & 7)] = 0;
    }

    // ---- QKR cluster: per-n batched weight loads (deep pipelining with 128-VGPR cap)
    f32x4 qa[4], ra[4], ka[4];
    #pragma unroll
    for (int n = 0; n < 4; ++n) { qa[n] = Z4; ra[n] = Z4; ka[n] = Z4; }
    f16x8 qhf[2];
    if (act) {
        #pragma unroll
        for (int n = 0; n < 4; ++n) {
            f16x8 bq[4], br[4], bk[4];
            #pragma unroll
            for (int t = 0; t < 4; ++t) {
                bq[t] = load_wfrag(wqh, t, colb + n * 16, lg, lr);
                br[t] = load_wfrag(wrh, t, colb + n * 16, lg, lr);
                bk[t] = load_wfrag(wkh, t, colb + n * 16, lg, lr);
            }
            #pragma unroll
            for (int t = 0; t < 4; ++t) {
                qa[n] = mfma16h(aq[t], bq[t], qa[n]);
                ra[n] = mfma16h(aq[t], br[t], ra[n]);
                ka[n] = mfma16h(ak[t], bk[t], ka[n]);
            }
        }

        // ---- issue v input loads now (hidden under qc/kc writes + v cluster)
        #pragma unroll
        for (int t = 0; t < 4; ++t)
            av[t] = *reinterpret_cast<const f16x8*>(vp + t * 32 + lg * 8);

        // qc/kc writes (uncentered fp16) + q column-sum partials (pad rows excluded)
        #pragma unroll
        for (int n = 0; n < 4; ++n)
            #pragma unroll
            for (int j = 0; j < 4; ++j) {
                qc[(mt * 16 + lg * 4 + j) * 72 + n * 16 + lr] = f2h(qa[n][j]);
                kc[(mt * 16 + lg * 4 + j) * 72 + n * 16 + lr] = f2h(ka[n][j]);
            }
        #pragma unroll
        for (int n = 0; n < 4; ++n) {
            float p = 0.f;
            #pragma unroll
            for (int j = 0; j < 4; ++j) {
                int rowj = mt * 16 + lg * 4 + j;
                p += (rowj < S_) ? qa[n][j] : 0.f;
            }
            p += __shfl_xor(p, 16, 64);
            p += __shfl_xor(p, 32, 64);
            if (lg == 0) qmp[(w * 4 + n) * 16 + lr] = p;
        }

        // ---- v cluster: per-n batched loads -> vT, packed b64 writes
        #pragma unroll
        for (int n = 0; n < 4; ++n) {
            f16x8 bv[4];
            #pragma unroll
            for (int t = 0; t < 4; ++t)
                bv[t] = load_wfrag(wvh, t, colb + n * 16, lg, lr);
            f32x4 va = Z4;
            #pragma unroll
            for (int t = 0; t < 4; ++t)
                va = mfma16h(av[t], bv[t], va);
            int r0 = mt * 16 + lg * 4;
            int d = n * 16 + lr;
            ushort4 o = { f2h(va[0]), f2h(va[1]), f2h(va[2]), f2h(va[3]) };
            *reinterpret_cast<ushort4*>(vT + d * 128 + (((r0 >> 3) ^ (d & 7)) << 3) + (r0 & 7)) = o;
        }

        // ---- pair A-frag: own-wave rows, written by this wave -> safe pre-barrier read
        #pragma unroll
        for (int t = 0; t < 2; ++t)
            qhf[t] = *reinterpret_cast<const f16x8*>(qc + (mt * 16 + lr) * 72 + t * 32 + lg * 8);
    }

    __syncthreads();                           // B1: qmp/qc/kc/vT visible

    // ---- post-B1 window: rj (VALU) + pair (MFMA) on act waves; uwv on wave 7
    f32x4 z[7];
    #pragma unroll
    for (int n = 0; n < 7; ++n) z[n] = Z4;
    if (act) {
        float qbar[4];
        #pragma unroll
        for (int n = 0; n < 4; ++n) {
            float s = 0.f;
            #pragma unroll
            for (int wv = 0; wv < 7; ++wv) s += qmp[(wv * 4 + n) * 16 + lr];
            qbar[n] = s * (1.f / S_);
        }
        float pr[4];
        #pragma unroll
        for (int j = 0; j < 4; ++j) {
            float s = 0.f;
            #pragma unroll
            for (int n = 0; n < 4; ++n) s += qbar[n] * ka[n][j];
            pr[j] = s;
        }
        #pragma unroll
        for (int o = 1; o < 16; o <<= 1)
            #pragma unroll
            for (int j = 0; j < 4; ++j) pr[j] += __shfl_xor(pr[j], o, 16);
        if (lr == 0)
            #pragma unroll
            for (int j = 0; j < 4; ++j) rbuf[mt * 16 + lg * 4 + j] = pr[j];

        #pragma unroll
        for (int n = 0; n < 7; ++n)
            #pragma unroll
            for (int t = 0; t < 2; ++t) {
                f16x8 bh = *reinterpret_cast<const f16x8*>(kc + (n * 16 + lr) * 72 + t * 32 + lg * 8);
                z[n] = mfma16h(qhf[t], bh, z[n]);
            }
    } else {
        const int d = l;
        float acc = 0.f;
        #pragma unroll
        for (int c = 0; c < 13; ++c) {         // chunks 0..12; subuf[100..111] = 0
            f16x8 vv = *reinterpret_cast<const f16x8*>(vT + d * 128 + ((c ^ (d & 7)) << 3));
            #pragma unroll
            for (int j = 0; j < 8; ++j) acc += subuf[c * 8 + j] * (float)vv[j];
        }
        uwvb[d] = acc;
    }
    __syncthreads();                           // B2: rbuf (and uwvb) visible

    // ---- subtract r_j, mask invalid cols, softmax over k (in-register)
    if (act) {
        #pragma unroll
        for (int n = 0; n < 7; ++n) {
            float rr = rbuf[n * 16 + lr];
            #pragma unroll
            for (int j = 0; j < 4; ++j) z[n][j] -= rr;
        }
        if (lr >= 4) {                         // cols 100..111 invalid
            f32x4 NEG = { -1e30f, -1e30f, -1e30f, -1e30f };
            z[6] = NEG;
        }
        #pragma unroll
        for (int j = 0; j < 4; ++j) {
            float m = z[0][j];
            #pragma unroll
            for (int n = 1; n < 7; ++n) m = fmaxf(m, z[n][j]);
            #pragma unroll
            for (int o = 1; o < 16; o <<= 1) m = fmaxf(m, __shfl_xor(m, o, 16));
            float s = 0.f;
            #pragma unroll
            for (int n = 0; n < 7; ++n) { float p = __expf(z[n][j] - m); z[n][j] = p; s += p; }
            #pragma unroll
            for (int o = 1; o < 16; o <<= 1) s += __shfl_xor(s, o, 16);
            float inv = 1.f / s;
            #pragma unroll
            for (int n = 0; n < 7; ++n) z[n][j] *= inv;
        }
    }
    __syncthreads();                           // B3: all qc/kc reads done (pl aliases qc/kc)

    // ---- write P (fp16 RNE); cols 112..127 zeroed
    if (act) {
        #pragma unroll
        for (int n = 0; n < 7; ++n)
            #pragma unroll
            for (int j = 0; j < 4; ++j) {
                int r = mt * 16 + lg * 4 + j;
                pl[r * 136 + n * 16 + lr] = f2h(z[n][j]);
            }
        #pragma unroll
        for (int j = 0; j < 4; ++j) {
            int r = mt * 16 + lg * 4 + j;
            pl[r * 136 + 112 + lr] = 0;
        }
    }
    __syncthreads();                           // B4: P + vT + uwvb ready

    // ---- PV (fp16) + epilogue
    if (act) {
        f16x8 pa[4];
        #pragma unroll
        for (int t = 0; t < 4; ++t)
            pa[t] = *reinterpret_cast<const f16x8*>(pl + (mt * 16 + lr) * 136 + t * 32 + lg * 8);
        f32x4 pv[4];
        #pragma unroll
        for (int n = 0; n < 4; ++n) pv[n] = Z4;
        #pragma unroll
        for (int n = 0; n < 4; ++n)
            #pragma unroll
            for (int t = 0; t < 4; ++t) {
                int d = n * 16 + lr;
                f16x8 bv = *reinterpret_cast<const f16x8*>(vT + d * 128 + ((((t * 4 + lg)) ^ (d & 7)) << 3));
                pv[n] = mfma16h(pa[t], bv, pv[n]);
            }

        #pragma unroll
        for (int n = 0; n < 4; ++n) {
            int d = n * 16 + lr;
            float add = bres[colb + d] + uwvb[d];
            #pragma unroll
            for (int j = 0; j < 4; ++j) {
                int r = mt * 16 + lg * 4 + j;
                if (r < S_) {
                    float val = ra[n][j] + pv[n][j] + add;
                    __builtin_nontemporal_store(val, &out[((size_t)b * S_ + r) * A_ + colb + d]);
                }
            }
        }
    }
}

// ---------------- fallback fused kernel (fp32 inputs, 2-term q/k) — used only if ws too small ----------------
__global__ __launch_bounds__(256, 3) void fused8_kernel(
    const float* __restrict__ query, const float* __restrict__ key, const float* __restrict__ value,
    const float* __restrict__ bres, const float* __restrict__ su,
    const u16* __restrict__ wbuf, float* __restrict__ out)
{
    __shared__ u32 smem[12704];
    u16* qc   = (u16*)smem;
    u16* kc   = (u16*)(smem + 4032);
    u16* vT   = (u16*)(smem + 8064);
    float* qmp  = (float*)(smem + 12160);
    float* rbuf = qmp + 256;
    float* uwvb = rbuf + 112;
    float* subuf= uwvb + 64;
    u16* pl = (u16*)smem;

    const int bid = blockIdx.x;
    const int b = ((bid >> 5) << 3) | (bid & 7);
    const int h = (bid >> 3) & 3;
    const int g = h * B_ + b;
    const int tid = threadIdx.x;
    const int l = tid & 63, w = tid >> 6;
    const int lr = l & 15, lg = l >> 4;
    const int colb = h * 64;

    const float* Xq = query + (size_t)b * (S_ * E_);
    const float* Xk = key   + (size_t)b * (S_ * E_);
    const float* Xv = value + (size_t)b * (S_ * E_);

    const u16* wqh = wbuf;
    const u16* wkh = wbuf + 32768;
    const u16* wvh = wbuf + 65536;
    const u16* wrh = wbuf + 98304;

    const int mt0 = w;
    const int mt1 = (w < 3) ? (w + 4) : 3;
    const int mt[2] = { mt0, mt1 };
    const float dupg = (w == 3) ? 0.f : 1.f;
    const f32x4 Z4 = { 0.f, 0.f, 0.f, 0.f };

    const int row0 = mt0 * 16 + lr, row1 = mt1 * 16 + lr;
    const float msk[2] = { (row0 < S_) ? 1.f : 0.f, (row1 < S_) ? 1.f : 0.f };
    const float* qp[2] = { Xq + (size_t)((row0 < S_) ? row0 : S_ - 1) * E_,
                           Xq + (size_t)((row1 < S_) ? row1 : S_ - 1) * E_ };
    const float* kp[2] = { Xk + (size_t)((row0 < S_) ? row0 : S_ - 1) * E_,
                           Xk + (size_t)((row1 < S_) ? row1 : S_ - 1) * E_ };
    const float* vp[2] = { Xv + (size_t)((row0 < S_) ? row0 : S_ - 1) * E_,
                           Xv + (size_t)((row1 < S_) ? row1 : S_ - 1) * E_ };

    float4 qr[2][4][2], kr[2][4][2];
    #pragma unroll
    for (int im = 0; im < 2; ++im)
        #pragma unroll
        for (int t = 0; t < 4; ++t) {
            qr[im][t][0] = *reinterpret_cast<const float4*>(qp[im] + t * 32 + lg * 8);
            qr[im][t][1] = *reinterpret_cast<const float4*>(qp[im] + t * 32 + lg * 8 + 4);
        }
    #pragma unroll
    for (int im = 0; im < 2; ++im)
        #pragma unroll
        for (int t = 0; t < 4; ++t) {
            kr[im][t][0] = *reinterpret_cast<const float4*>(kp[im] + t * 32 + lg * 8);
            kr[im][t][1] = *reinterpret_cast<const float4*>(kp[im] + t * 32 + lg * 8 + 4);
        }

    if (tid < S_) subuf[tid] = su[(size_t)g * S_ + tid];
    else if (tid < 112) subuf[tid] = 0.f;
    #pragma unroll
    for (int i = 0; i < 4; ++i) {
        int q = tid * 4 + i;
        int d = q & 63, k = 112 + (q >> 6);
        vT[d * 128 + (((k >> 3) ^ (d & 7)) << 3) + (k & 7)] = 0;
    }

    f16x8 ah[2][4], al[2][4];
    #pragma unroll
    for (int im = 0; im < 2; ++im)
        #pragma unroll
        for (int t = 0; t < 4; ++t)
            split8h(qr[im][t][0], qr[im][t][1], msk[im], ah[im][t], al[im][t]);

    f32x4 qa[2][4], ra[2][4];
    #pragma unroll
    for (int im = 0; im < 2; ++im)
        #pragma unroll
        for (int n = 0; n < 4; ++n) { qa[im][n] = Z4; ra[im][n] = Z4; }
    #pragma unroll
    for (int n = 0; n < 4; ++n)
        #pragma unroll
        for (int t = 0; t < 4; ++t) {
            f16x8 bh = load_wfrag(wqh, t, colb + n * 16, lg, lr);
            f16x8 br = load_wfrag(wrh, t, colb + n * 16, lg, lr);
            #pragma unroll
            for (int im = 0; im < 2; ++im) {
                qa[im][n] = mfma16h(ah[im][t], bh, qa[im][n]);
                qa[im][n] = mfma16h(al[im][t], bh, qa[im][n]);
                ra[im][n] = mfma16h(ah[im][t], br, ra[im][n]);
            }
        }
    #pragma unroll
    for (int im = 0; im < 2; ++im)
        #pragma unroll
        for (int n = 0; n < 4; ++n)
            #pragma unroll
            for (int j = 0; j < 4; ++j)
                qc[(mt[im] * 16 + lg * 4 + j) * 72 + n * 16 + lr] = f2h(qa[im][n][j]);
    #pragma unroll
    for (int n = 0; n < 4; ++n) {
        float p = 0.f;
        #pragma unroll
        for (int j = 0; j < 4; ++j) p += qa[0][n][j];
        float p1 = 0.f;
        #pragma unroll
        for (int j = 0; j < 4; ++j) p1 += qa[1][n][j];
        p += dupg * p1;
        p += __shfl_xor(p, 16, 64);
        p += __shfl_xor(p, 32, 64);
        if (lg == 0) qmp[(w * 4 + n) * 16 + lr] = p;
    }

    float4 vr[2][4][2];
    #pragma unroll
    for (int im = 0; im < 2; ++im)
        #pragma unroll
        for (int t = 0; t < 4; ++t) {
            vr[im][t][0] = *reinterpret_cast<const float4*>(vp[im] + t * 32 + lg * 8);
            vr[im][t][1] = *reinterpret_cast<const float4*>(vp[im] + t * 32 + lg * 8 + 4);
        }
    #pragma unroll
    for (int im = 0; im < 2; ++im)
        #pragma unroll
        for (int t = 0; t < 4; ++t)
            split8h(kr[im][t][0], kr[im][t][1], msk[im], ah[im][t], al[im][t]);

    f32x4 ka[2][4];
    #pragma unroll
    for (int im = 0; im < 2; ++im)
        #pragma unroll
        for (int n = 0; n < 4; ++n) ka[im][n] = Z4;
    #pragma unroll
    for (int n = 0; n < 4; ++n)
        #pragma unroll
        for (int t = 0; t < 4; ++t) {
            f16x8 bh = load_wfrag(wkh, t, colb + n * 16, lg, lr);
            #pragma unroll
            for (int im = 0; im < 2; ++im) {
                ka[im][n] = mfma16h(ah[im][t], bh, ka[im][n]);
                ka[im][n] = mfma16h(al[im][t], bh, ka[im][n]);
            }
        }
    #pragma unroll
    for (int im = 0; im < 2; ++im)
        #pragma unroll
        for (int n = 0; n < 4; ++n)
            #pragma unroll
            for (int j = 0; j < 4; ++j)
                kc[(mt[im] * 16 + lg * 4 + j) * 72 + n * 16 + lr] = f2h(ka[im][n][j]);

    __syncthreads();

    {
        float qbar[4];
        #pragma unroll
        for (int n = 0; n < 4; ++n) {
            float s = 0.f;
            #pragma unroll
            for (int wv = 0; wv < 4; ++wv) s += qmp[(wv * 4 + n) * 16 + lr];
            qbar[n] = s * (1.f / S_);
        }
        #pragma unroll
        for (int im = 0; im < 2; ++im) {
            float pr[4];
            #pragma unroll
            for (int j = 0; j < 4; ++j) {
                float s = 0.f;
                #pragma unroll
                for (int n = 0; n < 4; ++n) s += qbar[n] * ka[im][n][j];
                pr[j] = s;
            }
            #pragma unroll
            for (int o = 1; o < 16; o <<= 1)
                #pragma unroll
                for (int j = 0; j < 4; ++j) pr[j] += __shfl_xor(pr[j], o, 16);
            if (lr == 0)
                #pragma unroll
                for (int j = 0; j < 4; ++j) rbuf[mt[im] * 16 + lg * 4 + j] = pr[j];
        }
    }

    #pragma unroll
    for (int im = 0; im < 2; ++im)
        #pragma unroll
        for (int t = 0; t < 4; ++t)
            pack8h(vr[im][t][0], vr[im][t][1], msk[im], ah[im][t]);
    {
        f32x4 va[2][4];
        #pragma unroll
        for (int im = 0; im < 2; ++im)
            #pragma unroll
            for (int n = 0; n < 4; ++n) va[im][n] = Z4;
        #pragma unroll
        for (int n = 0; n < 4; ++n)
            #pragma unroll
            for (int t = 0; t < 4; ++t) {
                f16x8 bh = load_wfrag(wvh, t, colb + n * 16, lg, lr);
                #pragma unroll
                for (int im = 0; im < 2; ++im)
                    va[im][n] = mfma16h(ah[im][t], bh, va[im][n]);
            }
        #pragma unroll
        for (int im = 0; im < 2; ++im)
            #pragma unroll
            for (int n = 0; n < 4; ++n)
                #pragma unroll
                for (int j = 0; j < 4; ++j) {
                    int r = mt[im] * 16 + lg * 4 + j;
                    int d = n * 16 + lr;
                    vT[d * 128 + (((r >> 3) ^ (d & 7)) << 3) + (r & 7)] = f2h(va[im][n][j]);
                }
    }
    __syncthreads();

    f16x8 qhf[2][2];
    #pragma unroll
    for (int im = 0; im < 2; ++im)
        #pragma unroll
        for (int t = 0; t < 2; ++t)
            qhf[im][t] = *reinterpret_cast<const f16x8*>(qc + (mt[im] * 16 + lr) * 72 + t * 32 + lg * 8);
    f32x4 z[2][7];
    #pragma unroll
    for (int im = 0; im < 2; ++im)
        #pragma unroll
        for (int n = 0; n < 7; ++n) z[im][n] = Z4;
    #pragma unroll
    for (int n = 0; n < 7; ++n)
        #pragma unroll
        for (int t = 0; t < 2; ++t) {
            f16x8 bh = *reinterpret_cast<const f16x8*>(kc + (n * 16 + lr) * 72 + t * 32 + lg * 8);
            #pragma unroll
            for (int im = 0; im < 2; ++im)
                z[im][n] = mfma16h(qhf[im][t], bh, z[im][n]);
        }

    {
        const int d = w * 16 + lr;
        float acc = 0.f;
        #pragma unroll
        for (int c = 0; c < 3; ++c) {
            int k8 = lg + c * 4;
            f16x8 vv = *reinterpret_cast<const f16x8*>(vT + d * 128 + ((k8 ^ (d & 7)) << 3));
            #pragma unroll
            for (int j = 0; j < 8; ++j) acc += subuf[k8 * 8 + j] * (float)vv[j];
        }
        if (lg == 0) {
            f16x8 vv = *reinterpret_cast<const f16x8*>(vT + d * 128 + ((12 ^ (d & 7)) << 3));
            #pragma unroll
            for (int j = 0; j < 8; ++j) acc += subuf[96 + j] * (float)vv[j];
        }
        acc += __shfl_xor(acc, 16, 64);
        acc += __shfl_xor(acc, 32, 64);
        if (lg == 0) uwvb[d] = acc;
    }

    #pragma unroll
    for (int im = 0; im < 2; ++im) {
        #pragma unroll
        for (int n = 0; n < 7; ++n) {
            float rr = rbuf[n * 16 + lr];
            #pragma unroll
            for (int j = 0; j < 4; ++j) z[im][n][j] -= rr;
        }
        if (lr >= 4) {
            f32x4 NEG = { -1e30f, -1e30f, -1e30f, -1e30f };
            z[im][6] = NEG;
        }
        #pragma unroll
        for (int j = 0; j < 4; ++j) {
            float m = z[im][0][j];
            #pragma unroll
            for (int n = 1; n < 7; ++n) m = fmaxf(m, z[im][n][j]);
            #pragma unroll
            for (int o = 1; o < 16; o <<= 1) m = fmaxf(m, __shfl_xor(m, o, 16));
            float s = 0.f;
            #pragma unroll
            for (int n = 0; n < 7; ++n) { float p = __expf(z[im][n][j] - m); z[im][n][j] = p; s += p; }
            #pragma unroll
            for (int o = 1; o < 16; o <<= 1) s += __shfl_xor(s, o, 16);
            float inv = 1.f / s;
            #pragma unroll
            for (int n = 0; n < 7; ++n) z[im][n][j] *= inv;
        }
    }
    __syncthreads();

    #pragma unroll
    for (int im = 0; im < 2; ++im) {
        #pragma unroll
        for (int n = 0; n < 7; ++n)
            #pragma unroll
            for (int j = 0; j < 4; ++j) {
                int row = mt[im] * 16 + lg * 4 + j;
                pl[row * 136 + n * 16 + lr] = f2h(z[im][n][j]);
            }
        #pragma unroll
        for (int j = 0; j < 4; ++j) {
            int row = mt[im] * 16 + lg * 4 + j;
            pl[row * 136 + 112 + lr] = 0;
        }
    }
    __syncthreads();

    f16x8 pa[2][4];
    #pragma unroll
    for (int im = 0; im < 2; ++im)
        #pragma unroll
        for (int t = 0; t < 4; ++t)
            pa[im][t] = *reinterpret_cast<const f16x8*>(pl + (mt[im] * 16 + lr) * 136 + t * 32 + lg * 8);
    f32x4 pv[2][4];
    #pragma unroll
    for (int im = 0; im < 2; ++im)
        #pragma unroll
        for (int n = 0; n < 4; ++n) pv[im][n] = Z4;
    #pragma unroll
    for (int n = 0; n < 4; ++n)
        #pragma unroll
        for (int t = 0; t < 4; ++t) {
            int d = n * 16 + lr;
            f16x8 bv = *reinterpret_cast<const f16x8*>(vT + d * 128 + ((((t * 4 + lg)) ^ (d & 7)) << 3));
            #pragma unroll
            for (int im = 0; im < 2; ++im)
                pv[im][n] = mfma16h(pa[im][t], bv, pv[im][n]);
        }

    float bv4[4];
    #pragma unroll
    for (int n = 0; n < 4; ++n) bv4[n] = bres[colb + n * 16 + lr];
    #pragma unroll
    for (int im = 0; im < 2; ++im)
        #pragma unroll
        for (int n = 0; n < 4; ++n) {
            int d = n * 16 + lr;
            float add = bv4[n] + uwvb[d];
            #pragma unroll
            for (int j = 0; j < 4; ++j) {
                int row = mt[im] * 16 + lg * 4 + j;
                if (row < S_) {
                    float val = ra[im][n][j] + pv[im][n][j] + add;
                    __builtin_nontemporal_store(val, &out[((size_t)b * S_ + row) * A_ + colb + d]);
                }
            }
        }
}

extern "C" void kernel_launch(void* const* d_in, const int* in_sizes, int n_in,
                              void* d_out, int out_size, void* d_ws, size_t ws_size,
                              hipStream_t stream) {
    const float* query = (const float*)d_in[0];
    const float* key   = (const float*)d_in[1];
    const float* value = (const float*)d_in[2];
    const float* Wq    = (const float*)d_in[3];
    const float* Wk    = (const float*)d_in[4];
    const float* Wv    = (const float*)d_in[5];
    const float* Wu    = (const float*)d_in[6];
    const float* Wres  = (const float*)d_in[7];
    const float* bres  = (const float*)d_in[8];
    float* out = (float*)d_out;

    float* su  = (float*)d_ws;                          // 1.6384 MB
    u16*  wbuf = (u16*)((char*)d_ws + 1638400);         // 4 * 64 KB fp16 weights
    u16*  x16  = (u16*)((char*)d_ws + 2162688);         // 3 * 25.6 MB fp16 q/k/v

    const size_t need = 2162688u + 3u * (size_t)B_ * S_ * E_ * 2u;   // ~80.8 MB

    prep2_kernel<<<1028, 256, 0, stream>>>(query, key, value, Wu, Wq, Wk, Wv, Wres, su, wbuf, x16);
    if (ws_size >= need) {
        fusedD_kernel<<<B_ * H_, 512, 0, stream>>>(
            x16, x16 + (size_t)B_ * S_ * E_, x16 + 2u * (size_t)B_ * S_ * E_,
            bres, su, wbuf, out);
    } else {
        fused8_kernel<<<B_ * H_, 256, 0, stream>>>(query, key, value, bres, su, wbuf, out);
    }
}

// Round 15
// 175.535 us; speedup vs baseline: 1.1391x; 1.0672x over previous
//
#include <hip/hip_runtime.h>

#define B_ 1024
#define S_ 100
#define E_ 128
#define A_ 256
#define H_ 4

typedef __attribute__((ext_vector_type(4))) float f32x4;
typedef _Float16 f16;
typedef __attribute__((ext_vector_type(8))) _Float16 f16x8;
typedef unsigned short u16;
typedef unsigned int u32;

__device__ __forceinline__ u16 f2h(float x) {        // fp16 RNE, as bits
    return __builtin_bit_cast(u16, (f16)x);
}
__device__ __forceinline__ f32x4 mfma16h(f16x8 a, f16x8 b, f32x4 c) {
    return __builtin_amdgcn_mfma_f32_16x16x32_f16(a, b, c, 0, 0, 0);
}
// fp16 pack of 8 fp32 (RNE) — identical numerics to the old prep conversion
__device__ __forceinline__ void pack8(float4 a, float4 b, f16x8& hi) {
    float v[8] = { a.x, a.y, a.z, a.w, b.x, b.y, b.z, b.w };
    f16x8 H;
    #pragma unroll
    for (int j = 0; j < 8; ++j) H[j] = (f16)v[j];
    hi = H;
}
__device__ __forceinline__ f16x8 load_wfrag(const u16* wb, int t, int colbase, int lg, int lr) {
    return *reinterpret_cast<const f16x8*>(wb + ((((t * 4 + lg) * 256) + colbase + lr) << 3));
}

// ---------------- prep: blocks 0..1023 = unary softmax (su); 1024..1055 = fp16 weight prep ----------------
__global__ __launch_bounds__(256) void prep3_kernel(
    const float* __restrict__ key, const float* __restrict__ Wu,
    const float* __restrict__ Wq, const float* __restrict__ Wk,
    const float* __restrict__ Wv, const float* __restrict__ Wres,
    float* __restrict__ su, u16* __restrict__ wbuf)
{
    const int t = threadIdx.x;
    if (blockIdx.x >= 1024) {
        const int z8 = blockIdx.x - 1024;      // 32 blocks: 4 matrices x 8 parts
        const int z = z8 >> 3, part = z8 & 7;
        const float* src = (z == 0) ? Wq : (z == 1) ? Wk : (z == 2) ? Wv : Wres;
        u16* dst = wbuf + (size_t)z * 32768;
        for (int i = part * 4096 + t; i < (part + 1) * 4096; i += 256) {
            int e = i >> 8, col = i & 255;
            int ts = e >> 5, c = (e >> 3) & 3, j = e & 7;
            dst[(((ts * 4 + c) * 256 + col) << 3) + j] = f2h(src[i]);
        }
        return;
    }
    __shared__ float sm[S_ * H_];
    const int b = blockIdx.x;

    if (t < S_) {
        const float4* row = reinterpret_cast<const float4*>(key + ((size_t)b * S_ + t) * E_);
        const float4* wu4 = reinterpret_cast<const float4*>(Wu);
        float a0 = 0.f, a1 = 0.f, a2 = 0.f, a3 = 0.f;
        #pragma unroll 4
        for (int e4 = 0; e4 < E_ / 4; ++e4) {
            float4 kv = row[e4];
            float4 w0 = wu4[e4 * 4 + 0];
            float4 w1 = wu4[e4 * 4 + 1];
            float4 w2 = wu4[e4 * 4 + 2];
            float4 w3 = wu4[e4 * 4 + 3];
            a0 += kv.x * w0.x + kv.y * w1.x + kv.z * w2.x + kv.w * w3.x;
            a1 += kv.x * w0.y + kv.y * w1.y + kv.z * w2.y + kv.w * w3.y;
            a2 += kv.x * w0.z + kv.y * w1.z + kv.z * w2.z + kv.w * w3.z;
            a3 += kv.x * w0.w + kv.y * w1.w + kv.z * w2.w + kv.w * w3.w;
        }
        sm[t * 4 + 0] = a0; sm[t * 4 + 1] = a1;
        sm[t * 4 + 2] = a2; sm[t * 4 + 3] = a3;
    }
    __syncthreads();
    if (t < 128) {
        const int hh = t >> 5, i = t & 31;
        float m = -1e30f;
        for (int s = i; s < S_; s += 32) m = fmaxf(m, sm[s * 4 + hh]);
        #pragma unroll
        for (int o = 1; o < 32; o <<= 1) m = fmaxf(m, __shfl_xor(m, o, 32));
        float sum = 0.f;
        for (int s = i; s < S_; s += 32) sum += __expf(sm[s * 4 + hh] - m);
        #pragma unroll
        for (int o = 1; o < 32; o <<= 1) sum += __shfl_xor(sum, o, 32);
        float inv = 1.f / sum;
        for (int s = i; s < S_; s += 32) sm[s * 4 + hh] = __expf(sm[s * 4 + hh] - m) * inv;
    }
    __syncthreads();
    for (int i2 = t; i2 < S_ * H_; i2 += 256)
        su[(size_t)b * (S_ * H_) + i2] = sm[i2];
}

// ---------------- 8-wave fused kernel: fp32 inputs converted in-register (round-14 structure) ----------------
__global__ __launch_bounds__(512, 2) void fusedE_kernel(
    const float* __restrict__ query, const float* __restrict__ key, const float* __restrict__ value,
    const float* __restrict__ bres, const float* __restrict__ su,
    const u16* __restrict__ wbuf, float* __restrict__ out)
{
    __shared__ u32 smem[12896];               // 51584 B
    u16* qc   = (u16*)smem;                    // [112][72] fp16
    u16* kc   = (u16*)(smem + 4032);           // [112][72] fp16
    u16* vT   = (u16*)(smem + 8064);           // [64][128] fp16, xor-swz
    float* qmp  = (float*)(smem + 12160);      // [7][4][16] q col-sum partials
    float* rbuf = qmp + 448;                   // [112] r_j = qbar . k_j
    float* uwvb = rbuf + 112;                  // [64]
    float* subuf= uwvb + 64;                   // [112] su slice (tail zeroed)
    u16* pl = (u16*)smem;                      // P fp16 [112][136], aliases qc+kc

    const int bid = blockIdx.x;
    const int b = ((bid >> 5) << 3) | (bid & 7);   // XCD-grouped swizzle
    const int h = (bid >> 3) & 3;
    const int g = h * B_ + b;
    const int tid = threadIdx.x;
    const int l = tid & 63, w = tid >> 6;          // 8 waves
    const int lr = l & 15, lg = l >> 4;
    const int colb = h * 64;

    const float* Xq = query + (size_t)b * (S_ * E_);
    const float* Xk = key   + (size_t)b * (S_ * E_);
    const float* Xv = value + (size_t)b * (S_ * E_);

    const u16* wqh = wbuf;
    const u16* wkh = wbuf + 32768;
    const u16* wvh = wbuf + 65536;
    const u16* wrh = wbuf + 98304;

    const int mt = w;                          // waves 0..6 own tiles 0..6; wave 7 = aux
    const bool act = (w < 7);
    const f32x4 Z4 = { 0.f, 0.f, 0.f, 0.f };

    const int row = mt * 16 + lr;
    const int rowc = (row < S_) ? row : S_ - 1;
    const float* qp = Xq + (size_t)rowc * E_;
    const float* kp = Xk + (size_t)rowc * E_;
    const float* vp = Xv + (size_t)rowc * E_;

    // ---- issue q,k fp32 loads up front; convert in-register (same RNE cast as old prep)
    f16x8 aq[4], ak[4], av[4];
    if (act) {
        float4 qf[8], kf[8];
        #pragma unroll
        for (int t = 0; t < 4; ++t) {
            qf[2 * t]     = *reinterpret_cast<const float4*>(qp + t * 32 + lg * 8);
            qf[2 * t + 1] = *reinterpret_cast<const float4*>(qp + t * 32 + lg * 8 + 4);
        }
        #pragma unroll
        for (int t = 0; t < 4; ++t) {
            kf[2 * t]     = *reinterpret_cast<const float4*>(kp + t * 32 + lg * 8);
            kf[2 * t + 1] = *reinterpret_cast<const float4*>(kp + t * 32 + lg * 8 + 4);
        }
        #pragma unroll
        for (int t = 0; t < 4; ++t) pack8(qf[2 * t], qf[2 * t + 1], aq[t]);
        #pragma unroll
        for (int t = 0; t < 4; ++t) pack8(kf[2 * t], kf[2 * t + 1], ak[t]);
    }

    // ---- su slice -> LDS (tail zero); vT tail cols zero
    if (tid < S_) subuf[tid] = su[(size_t)g * S_ + tid];
    else if (tid < 112) subuf[tid] = 0.f;
    #pragma unroll
    for (int i = 0; i < 2; ++i) {
        int q = tid * 2 + i;                   // 0..1023
        int d = q & 63, k = 112 + (q >> 6);
        vT[d * 128 + (((k >> 3) ^ (d & 7)) << 3) + (k & 7)] = 0;
    }

    // ---- QKR cluster: per-n batched weight loads
    f32x4 qa[4], ra[4], ka[4];
    #pragma unroll
    for (int n = 0; n < 4; ++n) { qa[n] = Z4; ra[n] = Z4; ka[n] = Z4; }
    f16x8 qhf[2];
    if (act) {
        #pragma unroll
        for (int n = 0; n < 4; ++n) {
            f16x8 bq[4], br[4], bk[4];
            #pragma unroll
            for (int t = 0; t < 4; ++t) {
                bq[t] = load_wfrag(wqh, t, colb + n * 16, lg, lr);
                br[t] = load_wfrag(wrh, t, colb + n * 16, lg, lr);
                bk[t] = load_wfrag(wkh, t, colb + n * 16, lg, lr);
            }
            #pragma unroll
            for (int t = 0; t < 4; ++t) {
                qa[n] = mfma16h(aq[t], bq[t], qa[n]);
                ra[n] = mfma16h(aq[t], br[t], ra[n]);
                ka[n] = mfma16h(ak[t], bk[t], ka[n]);
            }
        }

        // ---- issue v fp32 loads now (hidden under qc/kc writes), convert before v cluster
        float4 vf[8];
        #pragma unroll
        for (int t = 0; t < 4; ++t) {
            vf[2 * t]     = *reinterpret_cast<const float4*>(vp + t * 32 + lg * 8);
            vf[2 * t + 1] = *reinterpret_cast<const float4*>(vp + t * 32 + lg * 8 + 4);
        }

        // qc/kc writes (uncentered fp16) + q column-sum partials (pad rows excluded)
        #pragma unroll
        for (int n = 0; n < 4; ++n)
            #pragma unroll
            for (int j = 0; j < 4; ++j) {
                qc[(mt * 16 + lg * 4 + j) * 72 + n * 16 + lr] = f2h(qa[n][j]);
                kc[(mt * 16 + lg * 4 + j) * 72 + n * 16 + lr] = f2h(ka[n][j]);
            }
        #pragma unroll
        for (int n = 0; n < 4; ++n) {
            float p = 0.f;
            #pragma unroll
            for (int j = 0; j < 4; ++j) {
                int rowj = mt * 16 + lg * 4 + j;
                p += (rowj < S_) ? qa[n][j] : 0.f;
            }
            p += __shfl_xor(p, 16, 64);
            p += __shfl_xor(p, 32, 64);
            if (lg == 0) qmp[(w * 4 + n) * 16 + lr] = p;
        }

        #pragma unroll
        for (int t = 0; t < 4; ++t) pack8(vf[2 * t], vf[2 * t + 1], av[t]);

        // ---- v cluster: per-n batched loads -> vT, packed b64 writes
        #pragma unroll
        for (int n = 0; n < 4; ++n) {
            f16x8 bv[4];
            #pragma unroll
            for (int t = 0; t < 4; ++t)
                bv[t] = load_wfrag(wvh, t, colb + n * 16, lg, lr);
            f32x4 va = Z4;
            #pragma unroll
            for (int t = 0; t < 4; ++t)
                va = mfma16h(av[t], bv[t], va);
            int r0 = mt * 16 + lg * 4;
            int d = n * 16 + lr;
            ushort4 o = { f2h(va[0]), f2h(va[1]), f2h(va[2]), f2h(va[3]) };
            *reinterpret_cast<ushort4*>(vT + d * 128 + (((r0 >> 3) ^ (d & 7)) << 3) + (r0 & 7)) = o;
        }

        // ---- pair A-frag: own-wave rows, written by this wave -> safe pre-barrier read
        #pragma unroll
        for (int t = 0; t < 2; ++t)
            qhf[t] = *reinterpret_cast<const f16x8*>(qc + (mt * 16 + lr) * 72 + t * 32 + lg * 8);
    }

    __syncthreads();                           // B1: qmp/qc/kc/vT visible

    // ---- post-B1 window: rj (VALU) + pair (MFMA) on act waves; uwv on wave 7
    f32x4 z[7];
    #pragma unroll
    for (int n = 0; n < 7; ++n) z[n] = Z4;
    if (act) {
        float qbar[4];
        #pragma unroll
        for (int n = 0; n < 4; ++n) {
            float s = 0.f;
            #pragma unroll
            for (int wv = 0; wv < 7; ++wv) s += qmp[(wv * 4 + n) * 16 + lr];
            qbar[n] = s * (1.f / S_);
        }
        float pr[4];
        #pragma unroll
        for (int j = 0; j < 4; ++j) {
            float s = 0.f;
            #pragma unroll
            for (int n = 0; n < 4; ++n) s += qbar[n] * ka[n][j];
            pr[j] = s;
        }
        #pragma unroll
        for (int o = 1; o < 16; o <<= 1)
            #pragma unroll
            for (int j = 0; j < 4; ++j) pr[j] += __shfl_xor(pr[j], o, 16);
        if (lr == 0)
            #pragma unroll
            for (int j = 0; j < 4; ++j) rbuf[mt * 16 + lg * 4 + j] = pr[j];

        #pragma unroll
        for (int n = 0; n < 7; ++n)
            #pragma unroll
            for (int t = 0; t < 2; ++t) {
                f16x8 bh = *reinterpret_cast<const f16x8*>(kc + (n * 16 + lr) * 72 + t * 32 + lg * 8);
                z[n] = mfma16h(qhf[t], bh, z[n]);
            }
    } else {
        const int d = l;
        float acc = 0.f;
        #pragma unroll
        for (int c = 0; c < 13; ++c) {         // chunks 0..12; subuf[100..111] = 0
            f16x8 vv = *reinterpret_cast<const f16x8*>(vT + d * 128 + ((c ^ (d & 7)) << 3));
            #pragma unroll
            for (int j = 0; j < 8; ++j) acc += subuf[c * 8 + j] * (float)vv[j];
        }
        uwvb[d] = acc;
    }
    __syncthreads();                           // B2: rbuf (and uwvb) visible

    // ---- subtract r_j, mask invalid cols, softmax over k (in-register)
    if (act) {
        #pragma unroll
        for (int n = 0; n < 7; ++n) {
            float rr = rbuf[n * 16 + lr];
            #pragma unroll
            for (int j = 0; j < 4; ++j) z[n][j] -= rr;
        }
        if (lr >= 4) {                         // cols 100..111 invalid
            f32x4 NEG = { -1e30f, -1e30f, -1e30f, -1e30f };
            z[6] = NEG;
        }
        #pragma unroll
        for (int j = 0; j < 4; ++j) {
            float m = z[0][j];
            #pragma unroll
            for (int n = 1; n < 7; ++n) m = fmaxf(m, z[n][j]);
            #pragma unroll
            for (int o = 1; o < 16; o <<= 1) m = fmaxf(m, __shfl_xor(m, o, 16));
            float s = 0.f;
            #pragma unroll
            for (int n = 0; n < 7; ++n) { float p = __expf(z[n][j] - m); z[n][j] = p; s += p; }
            #pragma unroll
            for (int o = 1; o < 16; o <<= 1) s += __shfl_xor(s, o, 16);
            float inv = 1.f / s;
            #pragma unroll
            for (int n = 0; n < 7; ++n) z[n][j] *= inv;
        }
    }
    __syncthreads();                           // B3: all qc/kc reads done (pl aliases qc/kc)

    // ---- write P (fp16 RNE); cols 112..127 zeroed
    if (act) {
        #pragma unroll
        for (int n = 0; n < 7; ++n)
            #pragma unroll
            for (int j = 0; j < 4; ++j) {
                int r = mt * 16 + lg * 4 + j;
                pl[r * 136 + n * 16 + lr] = f2h(z[n][j]);
            }
        #pragma unroll
        for (int j = 0; j < 4; ++j) {
            int r = mt * 16 + lg * 4 + j;
            pl[r * 136 + 112 + lr] = 0;
        }
    }
    __syncthreads();                           // B4: P + vT + uwvb ready

    // ---- PV (fp16) + epilogue
    if (act) {
        f16x8 pa[4];
        #pragma unroll
        for (int t = 0; t < 4; ++t)
            pa[t] = *reinterpret_cast<const f16x8*>(pl + (mt * 16 + lr) * 136 + t * 32 + lg * 8);
        f32x4 pv[4];
        #pragma unroll
        for (int n = 0; n < 4; ++n) pv[n] = Z4;
        #pragma unroll
        for (int n = 0; n < 4; ++n)
            #pragma unroll
            for (int t = 0; t < 4; ++t) {
                int d = n * 16 + lr;
                f16x8 bv = *reinterpret_cast<const f16x8*>(vT + d * 128 + ((((t * 4 + lg)) ^ (d & 7)) << 3));
                pv[n] = mfma16h(pa[t], bv, pv[n]);
            }

        #pragma unroll
        for (int n = 0; n < 4; ++n) {
            int d = n * 16 + lr;
            float add = bres[colb + d] + uwvb[d];
            #pragma unroll
            for (int j = 0; j < 4; ++j) {
                int r = mt * 16 + lg * 4 + j;
                if (r < S_) {
                    float val = ra[n][j] + pv[n][j] + add;
                    __builtin_nontemporal_store(val, &out[((size_t)b * S_ + r) * A_ + colb + d]);
                }
            }
        }
    }
}

extern "C" void kernel_launch(void* const* d_in, const int* in_sizes, int n_in,
                              void* d_out, int out_size, void* d_ws, size_t ws_size,
                              hipStream_t stream) {
    const float* query = (const float*)d_in[0];
    const float* key   = (const float*)d_in[1];
    const float* value = (const float*)d_in[2];
    const float* Wq    = (const float*)d_in[3];
    const float* Wk    = (const float*)d_in[4];
    const float* Wv    = (const float*)d_in[5];
    const float* Wu    = (const float*)d_in[6];
    const float* Wres  = (const float*)d_in[7];
    const float* bres  = (const float*)d_in[8];
    float* out = (float*)d_out;

    float* su  = (float*)d_ws;                          // 1.6384 MB
    u16*  wbuf = (u16*)((char*)d_ws + 1638400);         // 4 * 64 KB fp16 weights

    prep3_kernel<<<1056, 256, 0, stream>>>(key, Wu, Wq, Wk, Wv, Wres, su, wbuf);
    fusedE_kernel<<<B_ * H_, 512, 0, stream>>>(query, key, value, bres, su, wbuf, out);
}